// Round 1
// baseline (1331.761 us; speedup 1.0000x reference)
//
#include <hip/hip_runtime.h>
#include <cstdint>
#include <cstddef>

#define N_NODES 30000
#define E_EDGES 480000
#define ETOT    510000   // E + N self-loops
#define IN_DIM  128
#define HID     256
#define HEADS   4
#define NEG_SLOPE 0.2f

static inline int cdiv(int a, int b){ return (a + b - 1) / b; }

// ---- ordered-uint encoding for float atomicMax (memset-0 == -inf) ----
__device__ __forceinline__ unsigned enc_f(float f) {
  unsigned u = __float_as_uint(f);
  return (u & 0x80000000u) ? ~u : (u | 0x80000000u);
}
__device__ __forceinline__ float dec_f(unsigned e) {
  return __uint_as_float((e & 0x80000000u) ? (e ^ 0x80000000u) : ~e);
}

// ---- f32 GEMM: C[n x 256] = A[n x K] @ W[K x 256] (+bias). 64x64 tile, 4x4/thread ----
template<int K>
__global__ __launch_bounds__(256) void gemm_bias(
    const float* __restrict__ A, const float* __restrict__ W,
    const float* __restrict__ bias, float* __restrict__ C, int n)
{
  __shared__ float As[16][65];
  __shared__ float Ws[16][65];
  const int bm = blockIdx.x * 64;
  const int bn = blockIdx.y * 64;
  const int tid = threadIdx.x;
  const int tm = (tid >> 4) << 2;   // 0..60
  const int tn = (tid & 15) << 2;   // 0..60
  const int lr = tid >> 2;          // 0..63 (A tile row)
  const int lk = (tid & 3) << 2;    // 0,4,8,12
  const int wk = tid >> 4;          // 0..15 (W tile k)
  const int wn = (tid & 15) << 2;
  float acc[4][4] = {};
  for (int k0 = 0; k0 < K; k0 += 16) {
    int ar = min(bm + lr, n - 1);   // clamp tail rows (value unused on write)
    float4 a = *(const float4*)&A[(size_t)ar * K + k0 + lk];
    As[lk + 0][lr] = a.x; As[lk + 1][lr] = a.y;
    As[lk + 2][lr] = a.z; As[lk + 3][lr] = a.w;
    float4 w = *(const float4*)&W[(size_t)(k0 + wk) * HID + bn + wn];
    Ws[wk][wn + 0] = w.x; Ws[wk][wn + 1] = w.y;
    Ws[wk][wn + 2] = w.z; Ws[wk][wn + 3] = w.w;
    __syncthreads();
    #pragma unroll
    for (int k = 0; k < 16; ++k) {
      float av[4], wv[4];
      #pragma unroll
      for (int i = 0; i < 4; ++i) av[i] = As[k][tm + i];
      #pragma unroll
      for (int j = 0; j < 4; ++j) wv[j] = Ws[k][tn + j];
      #pragma unroll
      for (int i = 0; i < 4; ++i)
        #pragma unroll
        for (int j = 0; j < 4; ++j)
          acc[i][j] += av[i] * wv[j];
    }
    __syncthreads();
  }
  #pragma unroll
  for (int i = 0; i < 4; ++i) {
    int row = bm + tm + i;
    if (row < n) {
      float4 o;
      o.x = acc[i][0]; o.y = acc[i][1]; o.z = acc[i][2]; o.w = acc[i][3];
      if (bias) {
        o.x += bias[bn + tn + 0]; o.y += bias[bn + tn + 1];
        o.z += bias[bn + tn + 2]; o.w += bias[bn + tn + 3];
      }
      *(float4*)&C[(size_t)row * HID + bn + tn] = o;
    }
  }
}

// ---- per-node attention logits: e_src[n,h] = sum_c h[n,h,c]*a_src[h,c] ----
__global__ __launch_bounds__(256) void attn_logits(
    const float* __restrict__ h, const float* __restrict__ asrc,
    const float* __restrict__ adst, float* __restrict__ esrc,
    float* __restrict__ edst)
{
  const int n = blockIdx.x;
  const int t = threadIdx.x;
  const int hh = t >> 6, lane = t & 63;
  float hv = h[(size_t)n * HID + t];
  float vs = hv * asrc[t];
  float vd = hv * adst[t];
  #pragma unroll
  for (int m = 32; m >= 1; m >>= 1) {
    vs += __shfl_xor(vs, m);
    vd += __shfl_xor(vd, m);
  }
  if (lane == 0) {
    esrc[n * HEADS + hh] = vs;
    edst[n * HEADS + hh] = vd;
  }
}

// ---- edge pass 1: segment max of leaky_relu logits per (dst, head) ----
__global__ __launch_bounds__(256) void edge_max(
    const int* __restrict__ ei, const float* __restrict__ esrc,
    const float* __restrict__ edst, unsigned* __restrict__ emax)
{
  int e = blockIdx.x * blockDim.x + threadIdx.x;
  if (e >= ETOT) return;
  int s, d;
  if (e < E_EDGES) { s = ei[e]; d = ei[E_EDGES + e]; }
  else             { s = d = e - E_EDGES; }
  #pragma unroll
  for (int hh = 0; hh < HEADS; ++hh) {
    float v = esrc[s * HEADS + hh] + edst[d * HEADS + hh];
    v = (v >= 0.f) ? v : NEG_SLOPE * v;
    atomicMax(&emax[d * HEADS + hh], enc_f(v));
  }
}

// ---- edge pass 2: one wave per edge; agg[dst] += h[src]*p, denom[dst] += p ----
__global__ __launch_bounds__(256) void edge_agg(
    const int* __restrict__ ei, const float* __restrict__ h,
    const float* __restrict__ esrc, const float* __restrict__ edst,
    const unsigned* __restrict__ emax, float* __restrict__ agg,
    float* __restrict__ denom)
{
  int wid = (blockIdx.x * blockDim.x + threadIdx.x) >> 6;
  int lane = threadIdx.x & 63;
  if (wid >= ETOT) return;
  int s, d;
  if (wid < E_EDGES) { s = ei[wid]; d = ei[E_EDGES + wid]; }
  else               { s = d = wid - E_EDGES; }
  float p[HEADS];
  #pragma unroll
  for (int hh = 0; hh < HEADS; ++hh) {
    float v = esrc[s * HEADS + hh] + edst[d * HEADS + hh];
    v = (v >= 0.f) ? v : NEG_SLOPE * v;
    p[hh] = __expf(v - dec_f(emax[d * HEADS + hh]));
  }
  if (lane < HEADS) atomicAdd(&denom[d * HEADS + lane], p[lane]);
  #pragma unroll
  for (int hh = 0; hh < HEADS; ++hh) {
    float val = h[(size_t)s * HID + hh * 64 + lane] * p[hh];
    atomicAdd(&agg[(size_t)d * HID + hh * 64 + lane], val);
  }
}

// ---- finalize: out = elu(layernorm(agg/denom + bias + resid)) ----
__global__ __launch_bounds__(256) void finalize(
    const float* __restrict__ agg, const float* __restrict__ denom,
    const float* __restrict__ bias, const float* __restrict__ resid,
    const float* __restrict__ gamma, const float* __restrict__ beta,
    float* __restrict__ out)
{
  const int n = blockIdx.x;
  const int t = threadIdx.x;
  const int hh = t >> 6;
  float v = agg[(size_t)n * HID + t] / denom[n * HEADS + hh]
          + bias[t] + resid[(size_t)n * HID + t];
  float s1 = v, s2 = v * v;
  #pragma unroll
  for (int m = 32; m >= 1; m >>= 1) {
    s1 += __shfl_xor(s1, m);
    s2 += __shfl_xor(s2, m);
  }
  __shared__ float a1[4], a2[4];
  if ((t & 63) == 0) { a1[t >> 6] = s1; a2[t >> 6] = s2; }
  __syncthreads();
  float S1 = a1[0] + a1[1] + a1[2] + a1[3];
  float S2 = a2[0] + a2[1] + a2[2] + a2[3];
  float mu = S1 * (1.f / HID);
  float var = S2 * (1.f / HID) - mu * mu;
  float r = rsqrtf(var + 1e-5f);
  float y = (v - mu) * r * gamma[t] + beta[t];
  y = (y > 0.f) ? y : expm1f(y);
  out[(size_t)n * HID + t] = y;
}

extern "C" void kernel_launch(void* const* d_in, const int* in_sizes, int n_in,
                              void* d_out, int out_size, void* d_ws, size_t ws_size,
                              hipStream_t stream) {
  const float* x   = (const float*)d_in[0];
  const int*   ei  = (const int*)d_in[1];
  const float* W1  = (const float*)d_in[2];
  const float* as1 = (const float*)d_in[3];
  const float* ad1 = (const float*)d_in[4];
  const float* b1  = (const float*)d_in[5];
  const float* W2  = (const float*)d_in[6];
  const float* as2 = (const float*)d_in[7];
  const float* ad2 = (const float*)d_in[8];
  const float* b2  = (const float*)d_in[9];
  const float* g1  = (const float*)d_in[10];
  const float* be1 = (const float*)d_in[11];
  const float* g2  = (const float*)d_in[12];
  const float* be2 = (const float*)d_in[13];
  const float* Wp  = (const float*)d_in[14];
  const float* bp  = (const float*)d_in[15];
  float* out = (float*)d_out;

  const size_t NODE_BUF = (size_t)N_NODES * HID * sizeof(float); // 30.72 MB
  const size_t NH_BUF   = (size_t)N_NODES * HEADS * sizeof(float);
  char* ws = (char*)d_ws;
  float*    bufA  = (float*)(ws);                       // h1 / h2
  float*    bufB  = (float*)(ws + NODE_BUF);            // resid / hA
  float*    bufC  = (float*)(ws + 2 * NODE_BUF);        // agg
  float*    esrc  = (float*)(ws + 3 * NODE_BUF);
  float*    edstb = (float*)(ws + 3 * NODE_BUF + NH_BUF);
  unsigned* emax  = (unsigned*)(ws + 3 * NODE_BUF + 2 * NH_BUF);
  float*    denom = (float*)(ws + 3 * NODE_BUF + 3 * NH_BUF);

  dim3 gemm_grid(cdiv(N_NODES, 64), HID / 64);

  // ================= Layer 1 =================
  hipMemsetAsync(emax, 0, NH_BUF, stream);
  hipMemsetAsync(denom, 0, NH_BUF, stream);
  hipMemsetAsync(bufC, 0, NODE_BUF, stream);

  gemm_bias<IN_DIM><<<gemm_grid, 256, 0, stream>>>(x, W1, nullptr, bufA, N_NODES);
  gemm_bias<IN_DIM><<<gemm_grid, 256, 0, stream>>>(x, Wp, bp, bufB, N_NODES);
  attn_logits<<<N_NODES, 256, 0, stream>>>(bufA, as1, ad1, esrc, edstb);
  edge_max<<<cdiv(ETOT, 256), 256, 0, stream>>>(ei, esrc, edstb, emax);
  edge_agg<<<cdiv(ETOT, 4), 256, 0, stream>>>(ei, bufA, esrc, edstb, emax, bufC, denom);
  // hA (ELU(LN(...))) written in-place over resid buffer (bufB)
  finalize<<<N_NODES, 256, 0, stream>>>(bufC, denom, b1, bufB, g1, be1, bufB);

  // ================= Layer 2 =================
  hipMemsetAsync(emax, 0, NH_BUF, stream);
  hipMemsetAsync(denom, 0, NH_BUF, stream);
  hipMemsetAsync(bufC, 0, NODE_BUF, stream);

  gemm_bias<HID><<<gemm_grid, 256, 0, stream>>>(bufB, W2, nullptr, bufA, N_NODES);
  attn_logits<<<N_NODES, 256, 0, stream>>>(bufA, as2, ad2, esrc, edstb);
  edge_max<<<cdiv(ETOT, 256), 256, 0, stream>>>(ei, esrc, edstb, emax);
  edge_agg<<<cdiv(ETOT, 4), 256, 0, stream>>>(ei, bufA, esrc, edstb, emax, bufC, denom);
  finalize<<<N_NODES, 256, 0, stream>>>(bufC, denom, b2, bufB, g2, be2, out);
}

// Round 2
// 523.209 us; speedup vs baseline: 2.5454x; 2.5454x over previous
//
#include <hip/hip_runtime.h>
#include <cstdint>
#include <cstddef>

#define N_NODES 30000
#define E_EDGES 480000
#define ETOT    510000   // E + N self-loops
#define IN_DIM  128
#define HID     256
#define HEADS   4
#define NEG_SLOPE 0.2f

static inline int cdiv(int a, int b){ return (a + b - 1) / b; }

// ---- f32 GEMM: C[n x 256] = A[n x K] @ W[K x 256] (+bias). 64x64 tile, 4x4/thread ----
template<int K>
__global__ __launch_bounds__(256) void gemm_bias(
    const float* __restrict__ A, const float* __restrict__ W,
    const float* __restrict__ bias, float* __restrict__ C, int n)
{
  __shared__ float As[16][65];
  __shared__ float Ws[16][65];
  const int bm = blockIdx.x * 64;
  const int bn = blockIdx.y * 64;
  const int tid = threadIdx.x;
  const int tm = (tid >> 4) << 2;
  const int tn = (tid & 15) << 2;
  const int lr = tid >> 2;
  const int lk = (tid & 3) << 2;
  const int wk = tid >> 4;
  const int wn = (tid & 15) << 2;
  float acc[4][4] = {};
  for (int k0 = 0; k0 < K; k0 += 16) {
    int ar = min(bm + lr, n - 1);
    float4 a = *(const float4*)&A[(size_t)ar * K + k0 + lk];
    As[lk + 0][lr] = a.x; As[lk + 1][lr] = a.y;
    As[lk + 2][lr] = a.z; As[lk + 3][lr] = a.w;
    float4 w = *(const float4*)&W[(size_t)(k0 + wk) * HID + bn + wn];
    Ws[wk][wn + 0] = w.x; Ws[wk][wn + 1] = w.y;
    Ws[wk][wn + 2] = w.z; Ws[wk][wn + 3] = w.w;
    __syncthreads();
    #pragma unroll
    for (int k = 0; k < 16; ++k) {
      float av[4], wv[4];
      #pragma unroll
      for (int i = 0; i < 4; ++i) av[i] = As[k][tm + i];
      #pragma unroll
      for (int j = 0; j < 4; ++j) wv[j] = Ws[k][tn + j];
      #pragma unroll
      for (int i = 0; i < 4; ++i)
        #pragma unroll
        for (int j = 0; j < 4; ++j)
          acc[i][j] += av[i] * wv[j];
    }
    __syncthreads();
  }
  #pragma unroll
  for (int i = 0; i < 4; ++i) {
    int row = bm + tm + i;
    if (row < n) {
      float4 o;
      o.x = acc[i][0]; o.y = acc[i][1]; o.z = acc[i][2]; o.w = acc[i][3];
      if (bias) {
        o.x += bias[bn + tn + 0]; o.y += bias[bn + tn + 1];
        o.z += bias[bn + tn + 2]; o.w += bias[bn + tn + 3];
      }
      *(float4*)&C[(size_t)row * HID + bn + tn] = o;
    }
  }
}

// ---- per-node attention logits ----
__global__ __launch_bounds__(256) void attn_logits(
    const float* __restrict__ h, const float* __restrict__ asrc,
    const float* __restrict__ adst, float* __restrict__ esrc,
    float* __restrict__ edst)
{
  const int n = blockIdx.x;
  const int t = threadIdx.x;
  const int hh = t >> 6, lane = t & 63;
  float hv = h[(size_t)n * HID + t];
  float vs = hv * asrc[t];
  float vd = hv * adst[t];
  #pragma unroll
  for (int m = 32; m >= 1; m >>= 1) {
    vs += __shfl_xor(vs, m);
    vd += __shfl_xor(vd, m);
  }
  if (lane == 0) {
    esrc[n * HEADS + hh] = vs;
    edst[n * HEADS + hh] = vd;
  }
}

// ================= CSR build (graph is identical for both layers) =================
__global__ __launch_bounds__(256) void deg_count(const int* __restrict__ ei,
                                                 int* __restrict__ deg)
{
  int e = blockIdx.x * blockDim.x + threadIdx.x;
  if (e >= ETOT) return;
  int d = (e < E_EDGES) ? ei[E_EDGES + e] : (e - E_EDGES);
  atomicAdd(&deg[d], 1);
}

// single-block exclusive scan over 30000 degrees -> rowptr[N+1], cursor copy
__global__ __launch_bounds__(1024) void scan_rowptr(const int* __restrict__ deg,
                                                    int* __restrict__ rowptr,
                                                    int* __restrict__ cursor)
{
  const int CE = 30;  // 1024*30 = 30720 >= 30000
  __shared__ int sc[1024];
  int t = threadIdx.x;
  int base = t * CE;
  int local[CE];
  int s = 0;
  #pragma unroll
  for (int i = 0; i < CE; ++i) {
    int idx = base + i;
    int v = (idx < N_NODES) ? deg[idx] : 0;
    local[i] = s;
    s += v;
  }
  sc[t] = s;
  __syncthreads();
  for (int o = 1; o < 1024; o <<= 1) {
    int v = (t >= o) ? sc[t - o] : 0;
    __syncthreads();
    sc[t] += v;
    __syncthreads();
  }
  int off = sc[t] - s;  // exclusive prefix of this thread's chunk
  #pragma unroll
  for (int i = 0; i < CE; ++i) {
    int idx = base + i;
    if (idx < N_NODES) {
      rowptr[idx] = off + local[i];
      cursor[idx] = off + local[i];
    }
  }
  if (t == 1023) rowptr[N_NODES] = off + s;  // == ETOT
}

__global__ __launch_bounds__(256) void scatter_edges(const int* __restrict__ ei,
                                                     int* __restrict__ cursor,
                                                     int* __restrict__ col)
{
  int e = blockIdx.x * blockDim.x + threadIdx.x;
  if (e >= ETOT) return;
  int s, d;
  if (e < E_EDGES) { s = ei[e]; d = ei[E_EDGES + e]; }
  else             { s = d = e - E_EDGES; }
  int pos = atomicAdd(&cursor[d], 1);
  col[pos] = s;
}

// ================= fused CSR aggregation + /denom + bias + resid + LN + ELU ===========
// one block (256 threads) per destination node; thread t owns channel t
__global__ __launch_bounds__(256) void gat_agg(
    const int* __restrict__ rowptr, const int* __restrict__ col,
    const float* __restrict__ h, const float* __restrict__ esrc,
    const float* __restrict__ edst, const float* __restrict__ bias,
    const float* __restrict__ resid, const float* __restrict__ gamma,
    const float* __restrict__ beta, float* __restrict__ out)
{
  const int d = blockIdx.x;
  const int t = threadIdx.x;
  const int wave = t >> 6, lane = t & 63;
  const int hc = t >> 6;           // head of this channel
  const int r0 = rowptr[d], r1 = rowptr[d + 1];

  float ed[HEADS];
  #pragma unroll
  for (int hh = 0; hh < HEADS; ++hh) ed[hh] = edst[d * HEADS + hh];

  // ---- pass 1: per-head segment max ----
  float m[HEADS];
  #pragma unroll
  for (int hh = 0; hh < HEADS; ++hh) m[hh] = -1e30f;
  for (int j = r0 + t; j < r1; j += 256) {
    int s = col[j];
    #pragma unroll
    for (int hh = 0; hh < HEADS; ++hh) {
      float v = esrc[s * HEADS + hh] + ed[hh];
      v = (v >= 0.f) ? v : NEG_SLOPE * v;
      m[hh] = fmaxf(m[hh], v);
    }
  }
  #pragma unroll
  for (int hh = 0; hh < HEADS; ++hh)
    #pragma unroll
    for (int mm = 32; mm >= 1; mm >>= 1)
      m[hh] = fmaxf(m[hh], __shfl_xor(m[hh], mm));
  __shared__ float mred[4][HEADS];
  if (lane == 0)
    #pragma unroll
    for (int hh = 0; hh < HEADS; ++hh) mred[wave][hh] = m[hh];
  __syncthreads();
  #pragma unroll
  for (int hh = 0; hh < HEADS; ++hh)
    m[hh] = fmaxf(fmaxf(mred[0][hh], mred[1][hh]), fmaxf(mred[2][hh], mred[3][hh]));

  // ---- pass 2: chunked p computation + channel accumulation ----
  __shared__ int   s_lds[256];
  __shared__ float p_lds[256 * HEADS];
  float acc = 0.f;
  float dpart[HEADS];
  #pragma unroll
  for (int hh = 0; hh < HEADS; ++hh) dpart[hh] = 0.f;

  for (int base = r0; base < r1; base += 256) {
    int cnt = min(256, r1 - base);
    __syncthreads();
    if (t < cnt) {
      int s = col[base + t];
      s_lds[t] = s;
      #pragma unroll
      for (int hh = 0; hh < HEADS; ++hh) {
        float v = esrc[s * HEADS + hh] + ed[hh];
        v = (v >= 0.f) ? v : NEG_SLOPE * v;
        float p = __expf(v - m[hh]);
        p_lds[t * HEADS + hh] = p;
        dpart[hh] += p;
      }
    }
    __syncthreads();
    for (int j = 0; j < cnt; ++j) {
      acc += h[(size_t)s_lds[j] * HID + t] * p_lds[j * HEADS + hc];
    }
  }

  // ---- denom reduction across block ----
  #pragma unroll
  for (int hh = 0; hh < HEADS; ++hh)
    #pragma unroll
    for (int mm = 32; mm >= 1; mm >>= 1)
      dpart[hh] += __shfl_xor(dpart[hh], mm);
  __shared__ float dred[4][HEADS];
  if (lane == 0)
    #pragma unroll
    for (int hh = 0; hh < HEADS; ++hh) dred[wave][hh] = dpart[hh];
  __syncthreads();
  float den = dred[0][hc] + dred[1][hc] + dred[2][hc] + dred[3][hc];

  // ---- fused finalize: /denom + bias + resid + LayerNorm + ELU ----
  float v = acc / den + bias[t] + resid[(size_t)d * HID + t];
  float s1 = v, s2 = v * v;
  #pragma unroll
  for (int mm = 32; mm >= 1; mm >>= 1) {
    s1 += __shfl_xor(s1, mm);
    s2 += __shfl_xor(s2, mm);
  }
  __shared__ float a1[4], a2[4];
  if (lane == 0) { a1[wave] = s1; a2[wave] = s2; }
  __syncthreads();
  float S1 = a1[0] + a1[1] + a1[2] + a1[3];
  float S2 = a2[0] + a2[1] + a2[2] + a2[3];
  float mu = S1 * (1.f / HID);
  float var = S2 * (1.f / HID) - mu * mu;
  float r = rsqrtf(var + 1e-5f);
  float y = (v - mu) * r * gamma[t] + beta[t];
  y = (y > 0.f) ? y : expm1f(y);
  out[(size_t)d * HID + t] = y;
}

extern "C" void kernel_launch(void* const* d_in, const int* in_sizes, int n_in,
                              void* d_out, int out_size, void* d_ws, size_t ws_size,
                              hipStream_t stream) {
  const float* x   = (const float*)d_in[0];
  const int*   ei  = (const int*)d_in[1];
  const float* W1  = (const float*)d_in[2];
  const float* as1 = (const float*)d_in[3];
  const float* ad1 = (const float*)d_in[4];
  const float* b1  = (const float*)d_in[5];
  const float* W2  = (const float*)d_in[6];
  const float* as2 = (const float*)d_in[7];
  const float* ad2 = (const float*)d_in[8];
  const float* b2  = (const float*)d_in[9];
  const float* g1  = (const float*)d_in[10];
  const float* be1 = (const float*)d_in[11];
  const float* g2  = (const float*)d_in[12];
  const float* be2 = (const float*)d_in[13];
  const float* Wp  = (const float*)d_in[14];
  const float* bp  = (const float*)d_in[15];
  float* out = (float*)d_out;

  const size_t NODE_BUF = (size_t)N_NODES * HID * sizeof(float); // 30.72 MB
  const size_t NH_BUF   = (size_t)N_NODES * HEADS * sizeof(float);
  char* ws = (char*)d_ws;
  float* bufA   = (float*)(ws);                       // h (post-GEMM features)
  float* bufB   = (float*)(ws + NODE_BUF);            // resid / hA
  float* esrc   = (float*)(ws + 2 * NODE_BUF);
  float* edstb  = (float*)(ws + 2 * NODE_BUF + NH_BUF);
  int*   deg    = (int*)  (ws + 2 * NODE_BUF + 2 * NH_BUF);
  int*   rowptr = (int*)  (ws + 2 * NODE_BUF + 2 * NH_BUF + (size_t)N_NODES * 4);
  int*   cursor = (int*)  (ws + 2 * NODE_BUF + 2 * NH_BUF + (size_t)(2 * N_NODES + 1) * 4);
  int*   col    = (int*)  (ws + 2 * NODE_BUF + 2 * NH_BUF + (size_t)(3 * N_NODES + 1) * 4);

  dim3 gemm_grid(cdiv(N_NODES, 64), HID / 64);

  // ---- CSR build (shared by both layers) ----
  hipMemsetAsync(deg, 0, (size_t)N_NODES * 4, stream);
  deg_count<<<cdiv(ETOT, 256), 256, 0, stream>>>(ei, deg);
  scan_rowptr<<<1, 1024, 0, stream>>>(deg, rowptr, cursor);
  scatter_edges<<<cdiv(ETOT, 256), 256, 0, stream>>>(ei, cursor, col);

  // ================= Layer 1 =================
  gemm_bias<IN_DIM><<<gemm_grid, 256, 0, stream>>>(x, W1, nullptr, bufA, N_NODES);
  gemm_bias<IN_DIM><<<gemm_grid, 256, 0, stream>>>(x, Wp, bp, bufB, N_NODES);
  attn_logits<<<N_NODES, 256, 0, stream>>>(bufA, as1, ad1, esrc, edstb);
  gat_agg<<<N_NODES, 256, 0, stream>>>(rowptr, col, bufA, esrc, edstb, b1, bufB,
                                       g1, be1, bufB);  // hA overwrites resid in-place

  // ================= Layer 2 =================
  gemm_bias<HID><<<gemm_grid, 256, 0, stream>>>(bufB, W2, nullptr, bufA, N_NODES);
  attn_logits<<<N_NODES, 256, 0, stream>>>(bufA, as2, ad2, esrc, edstb);
  gat_agg<<<N_NODES, 256, 0, stream>>>(rowptr, col, bufA, esrc, edstb, b2, bufB,
                                       g2, be2, out);
}

// Round 3
// 408.958 us; speedup vs baseline: 3.2565x; 1.2794x over previous
//
#include <hip/hip_runtime.h>
#include <cstdint>
#include <cstddef>

#define N_NODES 30000
#define E_EDGES 480000
#define ETOT    510000   // E + N self-loops
#define IN_DIM  128
#define HID     256
#define HEADS   4
#define NEG_SLOPE 0.2f

static inline int cdiv(int a, int b){ return (a + b - 1) / b; }

typedef short bf16x8 __attribute__((ext_vector_type(8)));
typedef float f32x4  __attribute__((ext_vector_type(4)));

__device__ __forceinline__ unsigned short f2bf(float f) {
  unsigned u = __float_as_uint(f);
  unsigned r = (u + 0x7FFFu + ((u >> 16) & 1u)) >> 16;   // RNE
  return (unsigned short)r;
}
__device__ __forceinline__ float bf2f(unsigned short s) {
  return __uint_as_float((unsigned)s << 16);
}

// ---- convert x (f32) -> bf16, 4 elems/thread ----
__global__ __launch_bounds__(256) void conv_x(const float* __restrict__ x,
                                              ushort* __restrict__ xb, int total4)
{
  int i = blockIdx.x * 256 + threadIdx.x;
  if (i >= total4) return;
  float4 v = ((const float4*)x)[i];
  ushort4 o;
  o.x = f2bf(v.x); o.y = f2bf(v.y); o.z = f2bf(v.z); o.w = f2bf(v.w);
  ((ushort4*)xb)[i] = o;
}

// ---- transpose W [K][256] f32 -> WT [256][K] bf16 ----
__global__ __launch_bounds__(256) void transpose_w(const float* __restrict__ W,
                                                   ushort* __restrict__ WT, int K)
{
  int k = blockIdx.x;
  int c = threadIdx.x;
  WT[(size_t)c * K + k] = f2bf(W[(size_t)k * 256 + c]);
}

// ---- bf16 MFMA GEMM: C[n x 256] = A[n x K] @ WT^T (+bias opt) ----
// block = 256 thr = 4 waves (2x2), block tile 128x128, wave tile 64x64
template<int K, bool OUT_BF16>
__global__ __launch_bounds__(256) void gemm_mfma(
    const ushort* __restrict__ A,    // [n][K] bf16
    const ushort* __restrict__ WT,   // [256][K] bf16
    const float* __restrict__ bias,  // nullable
    void* __restrict__ Cout, int n)
{
  const int wave = threadIdx.x >> 6;
  const int lane = threadIdx.x & 63;
  const int wr = wave >> 1, wc = wave & 1;
  const int brow = blockIdx.x * 128 + wr * 64;
  const int bcol = blockIdx.y * 128 + wc * 64;
  const int lrow = lane & 15;
  const int kgrp = lane >> 4;       // 0..3

  f32x4 acc[4][4] = {};
  for (int k0 = 0; k0 < K; k0 += 32) {
    const int kb = k0 + kgrp * 8;
    bf16x8 a[4], b[4];
    #pragma unroll
    for (int mi = 0; mi < 4; ++mi) {
      int r = brow + mi * 16 + lrow;
      r = min(r, n - 1);
      a[mi] = *(const bf16x8*)&A[(size_t)r * K + kb];
    }
    #pragma unroll
    for (int ni = 0; ni < 4; ++ni) {
      int c = bcol + ni * 16 + lrow;
      b[ni] = *(const bf16x8*)&WT[(size_t)c * K + kb];
    }
    #pragma unroll
    for (int mi = 0; mi < 4; ++mi)
      #pragma unroll
      for (int ni = 0; ni < 4; ++ni)
        acc[mi][ni] = __builtin_amdgcn_mfma_f32_16x16x32_bf16(a[mi], b[ni], acc[mi][ni], 0, 0, 0);
  }
  #pragma unroll
  for (int mi = 0; mi < 4; ++mi) {
    #pragma unroll
    for (int r = 0; r < 4; ++r) {
      int row = brow + mi * 16 + kgrp * 4 + r;
      if (row < n) {
        #pragma unroll
        for (int ni = 0; ni < 4; ++ni) {
          int colg = bcol + ni * 16 + lrow;
          float v = acc[mi][ni][r];
          if (bias) v += bias[colg];
          if (OUT_BF16) ((ushort*)Cout)[(size_t)row * HID + colg] = f2bf(v);
          else          ((float*) Cout)[(size_t)row * HID + colg] = v;
        }
      }
    }
  }
}

// ---- per-node attention logits (bf16 h) ----
__global__ __launch_bounds__(256) void attn_logits(
    const ushort* __restrict__ h, const float* __restrict__ asrc,
    const float* __restrict__ adst, float* __restrict__ esrc,
    float* __restrict__ edst)
{
  const int n = blockIdx.x;
  const int t = threadIdx.x;
  const int hh = t >> 6, lane = t & 63;
  float hv = bf2f(h[(size_t)n * HID + t]);
  float vs = hv * asrc[t];
  float vd = hv * adst[t];
  #pragma unroll
  for (int m = 32; m >= 1; m >>= 1) {
    vs += __shfl_xor(vs, m);
    vd += __shfl_xor(vd, m);
  }
  if (lane == 0) {
    esrc[n * HEADS + hh] = vs;
    edst[n * HEADS + hh] = vd;
  }
}

// ================= CSR build =================
__global__ __launch_bounds__(256) void deg_count(const int* __restrict__ ei,
                                                 int* __restrict__ deg)
{
  int e = blockIdx.x * blockDim.x + threadIdx.x;
  if (e >= ETOT) return;
  int d = (e < E_EDGES) ? ei[E_EDGES + e] : (e - E_EDGES);
  atomicAdd(&deg[d], 1);
}

__global__ __launch_bounds__(1024) void scan_rowptr(const int* __restrict__ deg,
                                                    int* __restrict__ rowptr,
                                                    int* __restrict__ cursor)
{
  const int CE = 30;
  __shared__ int sc[1024];
  int t = threadIdx.x;
  int base = t * CE;
  int local[CE];
  int s = 0;
  #pragma unroll
  for (int i = 0; i < CE; ++i) {
    int idx = base + i;
    int v = (idx < N_NODES) ? deg[idx] : 0;
    local[i] = s;
    s += v;
  }
  sc[t] = s;
  __syncthreads();
  for (int o = 1; o < 1024; o <<= 1) {
    int v = (t >= o) ? sc[t - o] : 0;
    __syncthreads();
    sc[t] += v;
    __syncthreads();
  }
  int off = sc[t] - s;
  #pragma unroll
  for (int i = 0; i < CE; ++i) {
    int idx = base + i;
    if (idx < N_NODES) {
      rowptr[idx] = off + local[i];
      cursor[idx] = off + local[i];
    }
  }
  if (t == 1023) rowptr[N_NODES] = off + s;
}

__global__ __launch_bounds__(256) void scatter_edges(const int* __restrict__ ei,
                                                     int* __restrict__ cursor,
                                                     int* __restrict__ col)
{
  int e = blockIdx.x * blockDim.x + threadIdx.x;
  if (e >= ETOT) return;
  int s, d;
  if (e < E_EDGES) { s = ei[e]; d = ei[E_EDGES + e]; }
  else             { s = d = e - E_EDGES; }
  int pos = atomicAdd(&cursor[d], 1);
  col[pos] = s;
}

// ========== fused CSR aggregation + /denom + bias + resid + LN + ELU ==========
template<bool WRITE_BF16>
__global__ __launch_bounds__(256) void gat_agg(
    const int* __restrict__ rowptr, const int* __restrict__ col,
    const ushort* __restrict__ h, const float* __restrict__ esrc,
    const float* __restrict__ edst, const float* __restrict__ bias,
    const float* __restrict__ resid, const float* __restrict__ gamma,
    const float* __restrict__ beta, float* __restrict__ out_f32,
    ushort* __restrict__ out_bf16)
{
  const int d = blockIdx.x;
  const int t = threadIdx.x;
  const int wave = t >> 6, lane = t & 63;
  const int hc = t >> 6;
  const int r0 = rowptr[d], r1 = rowptr[d + 1];

  float ed[HEADS];
  #pragma unroll
  for (int hh = 0; hh < HEADS; ++hh) ed[hh] = edst[d * HEADS + hh];

  // pass 1: per-head segment max
  float m[HEADS];
  #pragma unroll
  for (int hh = 0; hh < HEADS; ++hh) m[hh] = -1e30f;
  for (int j = r0 + t; j < r1; j += 256) {
    int s = col[j];
    #pragma unroll
    for (int hh = 0; hh < HEADS; ++hh) {
      float v = esrc[s * HEADS + hh] + ed[hh];
      v = (v >= 0.f) ? v : NEG_SLOPE * v;
      m[hh] = fmaxf(m[hh], v);
    }
  }
  #pragma unroll
  for (int hh = 0; hh < HEADS; ++hh)
    #pragma unroll
    for (int mm = 32; mm >= 1; mm >>= 1)
      m[hh] = fmaxf(m[hh], __shfl_xor(m[hh], mm));
  __shared__ float mred[4][HEADS];
  if (lane == 0)
    #pragma unroll
    for (int hh = 0; hh < HEADS; ++hh) mred[wave][hh] = m[hh];
  __syncthreads();
  #pragma unroll
  for (int hh = 0; hh < HEADS; ++hh)
    m[hh] = fmaxf(fmaxf(mred[0][hh], mred[1][hh]), fmaxf(mred[2][hh], mred[3][hh]));

  // pass 2: chunked p + channel accumulation (bf16 gather)
  __shared__ int   s_lds[256];
  __shared__ float p_lds[256 * HEADS];
  float acc = 0.f;
  float dpart[HEADS];
  #pragma unroll
  for (int hh = 0; hh < HEADS; ++hh) dpart[hh] = 0.f;

  for (int base = r0; base < r1; base += 256) {
    int cnt = min(256, r1 - base);
    __syncthreads();
    if (t < cnt) {
      int s = col[base + t];
      s_lds[t] = s;
      #pragma unroll
      for (int hh = 0; hh < HEADS; ++hh) {
        float v = esrc[s * HEADS + hh] + ed[hh];
        v = (v >= 0.f) ? v : NEG_SLOPE * v;
        float p = __expf(v - m[hh]);
        p_lds[t * HEADS + hh] = p;
        dpart[hh] += p;
      }
    }
    __syncthreads();
    for (int j = 0; j < cnt; ++j) {
      acc += bf2f(h[(size_t)s_lds[j] * HID + t]) * p_lds[j * HEADS + hc];
    }
  }

  // denom reduction
  #pragma unroll
  for (int hh = 0; hh < HEADS; ++hh)
    #pragma unroll
    for (int mm = 32; mm >= 1; mm >>= 1)
      dpart[hh] += __shfl_xor(dpart[hh], mm);
  __shared__ float dred[4][HEADS];
  if (lane == 0)
    #pragma unroll
    for (int hh = 0; hh < HEADS; ++hh) dred[wave][hh] = dpart[hh];
  __syncthreads();
  float den = dred[0][hc] + dred[1][hc] + dred[2][hc] + dred[3][hc];

  // fused finalize
  float v = acc / den + bias[t] + resid[(size_t)d * HID + t];
  float s1 = v, s2 = v * v;
  #pragma unroll
  for (int mm = 32; mm >= 1; mm >>= 1) {
    s1 += __shfl_xor(s1, mm);
    s2 += __shfl_xor(s2, mm);
  }
  __shared__ float a1[4], a2[4];
  if (lane == 0) { a1[wave] = s1; a2[wave] = s2; }
  __syncthreads();
  float S1 = a1[0] + a1[1] + a1[2] + a1[3];
  float S2 = a2[0] + a2[1] + a2[2] + a2[3];
  float mu = S1 * (1.f / HID);
  float var = S2 * (1.f / HID) - mu * mu;
  float r = rsqrtf(var + 1e-5f);
  float y = (v - mu) * r * gamma[t] + beta[t];
  y = (y > 0.f) ? y : expm1f(y);
  out_f32[(size_t)d * HID + t] = y;
  if (WRITE_BF16) out_bf16[(size_t)d * HID + t] = f2bf(y);
}

extern "C" void kernel_launch(void* const* d_in, const int* in_sizes, int n_in,
                              void* d_out, int out_size, void* d_ws, size_t ws_size,
                              hipStream_t stream) {
  const float* x   = (const float*)d_in[0];
  const int*   ei  = (const int*)d_in[1];
  const float* W1  = (const float*)d_in[2];
  const float* as1 = (const float*)d_in[3];
  const float* ad1 = (const float*)d_in[4];
  const float* b1  = (const float*)d_in[5];
  const float* W2  = (const float*)d_in[6];
  const float* as2 = (const float*)d_in[7];
  const float* ad2 = (const float*)d_in[8];
  const float* b2  = (const float*)d_in[9];
  const float* g1  = (const float*)d_in[10];
  const float* be1 = (const float*)d_in[11];
  const float* g2  = (const float*)d_in[12];
  const float* be2 = (const float*)d_in[13];
  const float* Wp  = (const float*)d_in[14];
  const float* bp  = (const float*)d_in[15];
  float* out = (float*)d_out;

  const size_t NB16 = (size_t)N_NODES * HID * sizeof(ushort);  // 15.36 MB
  const size_t NB32 = (size_t)N_NODES * HID * sizeof(float);   // 30.72 MB
  const size_t XB16 = (size_t)N_NODES * IN_DIM * sizeof(ushort);
  const size_t NH_BUF = (size_t)N_NODES * HEADS * sizeof(float);
  char* ws = (char*)d_ws;
  size_t off = 0;
  ushort* hbf   = (ushort*)(ws + off); off += NB16;            // h1 / h2 (bf16)
  ushort* hAbf  = (ushort*)(ws + off); off += NB16;            // hA (bf16)
  float*  bufB  = (float*) (ws + off); off += NB32;            // resid (f32)
  ushort* xbf   = (ushort*)(ws + off); off += XB16;
  ushort* w1t   = (ushort*)(ws + off); off += (size_t)HID * IN_DIM * 2;
  ushort* wpt   = (ushort*)(ws + off); off += (size_t)HID * IN_DIM * 2;
  ushort* w2t   = (ushort*)(ws + off); off += (size_t)HID * HID * 2;
  float*  esrc  = (float*) (ws + off); off += NH_BUF;
  float*  edstb = (float*) (ws + off); off += NH_BUF;
  int*    deg    = (int*)(ws + off); off += (size_t)N_NODES * 4;
  int*    rowptr = (int*)(ws + off); off += (size_t)(N_NODES + 1) * 4;
  int*    cursor = (int*)(ws + off); off += (size_t)N_NODES * 4;
  int*    col    = (int*)(ws + off); off += (size_t)ETOT * 4;

  // ---- CSR build ----
  hipMemsetAsync(deg, 0, (size_t)N_NODES * 4, stream);
  deg_count<<<cdiv(ETOT, 256), 256, 0, stream>>>(ei, deg);
  scan_rowptr<<<1, 1024, 0, stream>>>(deg, rowptr, cursor);
  scatter_edges<<<cdiv(ETOT, 256), 256, 0, stream>>>(ei, cursor, col);

  // ---- precision prep ----
  conv_x<<<cdiv(N_NODES * IN_DIM / 4, 256), 256, 0, stream>>>(x, xbf, N_NODES * IN_DIM / 4);
  transpose_w<<<IN_DIM, 256, 0, stream>>>(W1, w1t, IN_DIM);
  transpose_w<<<IN_DIM, 256, 0, stream>>>(Wp, wpt, IN_DIM);
  transpose_w<<<HID,    256, 0, stream>>>(W2, w2t, HID);

  dim3 gemm_grid(cdiv(N_NODES, 128), 2);

  // ================= Layer 1 =================
  gemm_mfma<IN_DIM, true ><<<gemm_grid, 256, 0, stream>>>(xbf, w1t, nullptr, hbf, N_NODES);
  gemm_mfma<IN_DIM, false><<<gemm_grid, 256, 0, stream>>>(xbf, wpt, bp, bufB, N_NODES);
  attn_logits<<<N_NODES, 256, 0, stream>>>(hbf, as1, ad1, esrc, edstb);
  gat_agg<true><<<N_NODES, 256, 0, stream>>>(rowptr, col, hbf, esrc, edstb, b1, bufB,
                                             g1, be1, bufB, hAbf);

  // ================= Layer 2 =================
  gemm_mfma<HID, true><<<gemm_grid, 256, 0, stream>>>(hAbf, w2t, nullptr, hbf, N_NODES);
  attn_logits<<<N_NODES, 256, 0, stream>>>(hbf, as2, ad2, esrc, edstb);
  gat_agg<false><<<N_NODES, 256, 0, stream>>>(rowptr, col, hbf, esrc, edstb, b2, bufB,
                                              g2, be2, out, nullptr);
}

// Round 4
// 352.493 us; speedup vs baseline: 3.7781x; 1.1602x over previous
//
#include <hip/hip_runtime.h>
#include <cstdint>
#include <cstddef>

#define N_NODES 30000
#define E_EDGES 480000
#define ETOT    510000   // E + N self-loops
#define IN_DIM  128
#define HID     256
#define HEADS   4
#define NEG_SLOPE 0.2f

static inline int cdiv(int a, int b){ return (a + b - 1) / b; }

typedef short bf16x8 __attribute__((ext_vector_type(8)));
typedef float f32x4  __attribute__((ext_vector_type(4)));

__device__ __forceinline__ unsigned short f2bf(float f) {
  unsigned u = __float_as_uint(f);
  unsigned r = (u + 0x7FFFu + ((u >> 16) & 1u)) >> 16;   // RNE
  return (unsigned short)r;
}
__device__ __forceinline__ float bf2f(unsigned short s) {
  return __uint_as_float((unsigned)s << 16);
}

// ---- prep: x->bf16 (3750 blocks) + W1/Wp/W2 transpose->bf16 ----
__global__ __launch_bounds__(256) void prep(
    const float* __restrict__ x, const float* __restrict__ W1,
    const float* __restrict__ Wp, const float* __restrict__ W2,
    ushort* __restrict__ xbf, ushort* __restrict__ w1t,
    ushort* __restrict__ wpt, ushort* __restrict__ w2t)
{
  int b = blockIdx.x;
  int t = threadIdx.x;
  if (b < 3750) {                       // 3750*256*4 = 3.84M = N*IN
    int i = b * 256 + t;
    float4 v = ((const float4*)x)[i];
    ushort4 o;
    o.x = f2bf(v.x); o.y = f2bf(v.y); o.z = f2bf(v.z); o.w = f2bf(v.w);
    ((ushort4*)xbf)[i] = o;
  } else if (b < 3750 + 128) {
    int k = b - 3750;
    w1t[(size_t)t * IN_DIM + k] = f2bf(W1[(size_t)k * HID + t]);
  } else if (b < 3750 + 256) {
    int k = b - 3878;
    wpt[(size_t)t * IN_DIM + k] = f2bf(Wp[(size_t)k * HID + t]);
  } else {
    int k = b - 4006;
    w2t[(size_t)t * HID + k] = f2bf(W2[(size_t)k * HID + t]);
  }
}

// ---- bf16 MFMA GEMM: C[n x 256] = A[n x K] @ WT^T (+bias opt) ----
template<int K, bool OUT_BF16>
__global__ __launch_bounds__(256) void gemm_mfma(
    const ushort* __restrict__ A,    // [n][K] bf16
    const ushort* __restrict__ WT,   // [256][K] bf16
    const float* __restrict__ bias,  // nullable
    void* __restrict__ Cout, int n)
{
  const int wave = threadIdx.x >> 6;
  const int lane = threadIdx.x & 63;
  const int wr = wave >> 1, wc = wave & 1;
  const int brow = blockIdx.x * 128 + wr * 64;
  const int bcol = blockIdx.y * 128 + wc * 64;
  const int lrow = lane & 15;
  const int kgrp = lane >> 4;       // 0..3

  f32x4 acc[4][4] = {};
  for (int k0 = 0; k0 < K; k0 += 32) {
    const int kb = k0 + kgrp * 8;
    bf16x8 a[4], b[4];
    #pragma unroll
    for (int mi = 0; mi < 4; ++mi) {
      int r = brow + mi * 16 + lrow;
      r = min(r, n - 1);
      a[mi] = *(const bf16x8*)&A[(size_t)r * K + kb];
    }
    #pragma unroll
    for (int ni = 0; ni < 4; ++ni) {
      int c = bcol + ni * 16 + lrow;
      b[ni] = *(const bf16x8*)&WT[(size_t)c * K + kb];
    }
    #pragma unroll
    for (int mi = 0; mi < 4; ++mi)
      #pragma unroll
      for (int ni = 0; ni < 4; ++ni)
        acc[mi][ni] = __builtin_amdgcn_mfma_f32_16x16x32_bf16(a[mi], b[ni], acc[mi][ni], 0, 0, 0);
  }
  #pragma unroll
  for (int mi = 0; mi < 4; ++mi) {
    #pragma unroll
    for (int r = 0; r < 4; ++r) {
      int row = brow + mi * 16 + kgrp * 4 + r;
      if (row < n) {
        #pragma unroll
        for (int ni = 0; ni < 4; ++ni) {
          int colg = bcol + ni * 16 + lrow;
          float v = acc[mi][ni][r];
          if (bias) v += bias[colg];
          if (OUT_BF16) ((ushort*)Cout)[(size_t)row * HID + colg] = f2bf(v);
          else          ((float*) Cout)[(size_t)row * HID + colg] = v;
        }
      }
    }
  }
}

// ---- per-node attention logits (bf16 h) ----
__global__ __launch_bounds__(256) void attn_logits(
    const ushort* __restrict__ h, const float* __restrict__ asrc,
    const float* __restrict__ adst, float* __restrict__ esrc,
    float* __restrict__ edst)
{
  const int n = blockIdx.x;
  const int t = threadIdx.x;
  const int hh = t >> 6, lane = t & 63;
  float hv = bf2f(h[(size_t)n * HID + t]);
  float vs = hv * asrc[t];
  float vd = hv * adst[t];
  #pragma unroll
  for (int m = 32; m >= 1; m >>= 1) {
    vs += __shfl_xor(vs, m);
    vd += __shfl_xor(vd, m);
  }
  if (lane == 0) {
    esrc[n * HEADS + hh] = vs;
    edst[n * HEADS + hh] = vd;
  }
}

// ================= CSR build =================
__global__ __launch_bounds__(256) void deg_count(const int* __restrict__ ei,
                                                 int* __restrict__ deg)
{
  int e = blockIdx.x * blockDim.x + threadIdx.x;
  if (e >= ETOT) return;
  int d = (e < E_EDGES) ? ei[E_EDGES + e] : (e - E_EDGES);
  atomicAdd(&deg[d], 1);
}

__global__ __launch_bounds__(1024) void scan_rowptr(const int* __restrict__ deg,
                                                    int* __restrict__ rowptr,
                                                    int* __restrict__ cursor)
{
  const int CE = 30;
  __shared__ int sc[1024];
  int t = threadIdx.x;
  int base = t * CE;
  int local[CE];
  int s = 0;
  #pragma unroll
  for (int i = 0; i < CE; ++i) {
    int idx = base + i;
    int v = (idx < N_NODES) ? deg[idx] : 0;
    local[i] = s;
    s += v;
  }
  sc[t] = s;
  __syncthreads();
  for (int o = 1; o < 1024; o <<= 1) {
    int v = (t >= o) ? sc[t - o] : 0;
    __syncthreads();
    sc[t] += v;
    __syncthreads();
  }
  int off = sc[t] - s;
  #pragma unroll
  for (int i = 0; i < CE; ++i) {
    int idx = base + i;
    if (idx < N_NODES) {
      rowptr[idx] = off + local[i];
      cursor[idx] = off + local[i];
    }
  }
  if (t == 1023) rowptr[N_NODES] = off + s;
}

__global__ __launch_bounds__(256) void scatter_edges(const int* __restrict__ ei,
                                                     int* __restrict__ cursor,
                                                     int* __restrict__ col,
                                                     int* __restrict__ dstc)
{
  int e = blockIdx.x * blockDim.x + threadIdx.x;
  if (e >= ETOT) return;
  int s, d;
  if (e < E_EDGES) { s = ei[e]; d = ei[E_EDGES + e]; }
  else             { s = d = e - E_EDGES; }
  int pos = atomicAdd(&cursor[d], 1);
  col[pos] = s;
  dstc[pos] = d;
}

// ---- per-edge p = exp(leaky(esrc[s]+edst[d])) in CSR order, 4 heads ----
__global__ __launch_bounds__(256) void edge_alpha(
    const int* __restrict__ col, const int* __restrict__ dstc,
    const float* __restrict__ esrc, const float* __restrict__ edst,
    float* __restrict__ pcsr)
{
  int j = blockIdx.x * 256 + threadIdx.x;
  if (j >= ETOT) return;
  int s = col[j], d = dstc[j];
  float4 es = ((const float4*)esrc)[s];
  float4 ed = ((const float4*)edst)[d];
  float4 p;
  float v;
  v = es.x + ed.x; v = (v >= 0.f) ? v : NEG_SLOPE * v; p.x = __expf(fminf(v, 60.f));
  v = es.y + ed.y; v = (v >= 0.f) ? v : NEG_SLOPE * v; p.y = __expf(fminf(v, 60.f));
  v = es.z + ed.z; v = (v >= 0.f) ? v : NEG_SLOPE * v; p.z = __expf(fminf(v, 60.f));
  v = es.w + ed.w; v = (v >= 0.f) ? v : NEG_SLOPE * v; p.w = __expf(fminf(v, 60.f));
  ((float4*)pcsr)[j] = p;
}

// ========== fused CSR aggregation + /denom + bias + resid + LN + ELU ==========
// block = 256 thr per dst node. thread t: edge-slot t>>5, channels (t&31)*8..+7
template<bool WRITE_BF16>
__global__ __launch_bounds__(256) void gat_agg(
    const int* __restrict__ rowptr, const int* __restrict__ col,
    const float* __restrict__ pcsr, const ushort* __restrict__ h,
    const float* __restrict__ bias, const float* __restrict__ resid,
    const float* __restrict__ gamma, const float* __restrict__ beta,
    float* __restrict__ out_f32, ushort* __restrict__ out_bf16)
{
  const int d = blockIdx.x;
  const int t = threadIdx.x;
  const int wave = t >> 6, lane = t & 63;
  const int slot = t >> 5;            // 0..7
  const int cblk = (t & 31) * 8;      // channel base
  const int headc = cblk >> 6;        // head of this channel block
  const int r0 = rowptr[d], r1 = rowptr[d + 1];

  __shared__ int    s_lds[256];
  __shared__ float4 p_lds[256];
  float acc[8] = {};
  float dp[HEADS] = {};

  for (int base = r0; base < r1; base += 256) {
    int cnt = min(256, r1 - base);
    __syncthreads();
    if (t < cnt) {
      s_lds[t] = col[base + t];
      float4 pv = ((const float4*)pcsr)[base + t];
      p_lds[t] = pv;
      dp[0] += pv.x; dp[1] += pv.y; dp[2] += pv.z; dp[3] += pv.w;
    }
    __syncthreads();
    for (int j = slot; j < cnt; j += 8) {
      int s = s_lds[j];
      bf16x8 hv = *(const bf16x8*)&h[(size_t)s * HID + cblk];
      float p = ((const float*)&p_lds[j])[headc];
      #pragma unroll
      for (int k = 0; k < 8; ++k) acc[k] += bf2f(hv[k]) * p;
    }
  }

  // denom reduction across block (per head)
  #pragma unroll
  for (int hh = 0; hh < HEADS; ++hh)
    #pragma unroll
    for (int mm = 32; mm >= 1; mm >>= 1)
      dp[hh] += __shfl_xor(dp[hh], mm);
  __shared__ float dred[4][HEADS];
  if (lane == 0)
    #pragma unroll
    for (int hh = 0; hh < HEADS; ++hh) dred[wave][hh] = dp[hh];

  // slot reduction: combine lane pairs l, l^32 (slots 2w / 2w+1)
  #pragma unroll
  for (int k = 0; k < 8; ++k) acc[k] += __shfl_xor(acc[k], 32);
  __shared__ float red[4][256];
  if (lane < 32) {
    #pragma unroll
    for (int k = 0; k < 8; ++k) red[wave][cblk + k] = acc[k];
  }
  __syncthreads();

  const int hc = t >> 6;
  float den = dred[0][hc] + dred[1][hc] + dred[2][hc] + dred[3][hc];
  float v = (red[0][t] + red[1][t] + red[2][t] + red[3][t]) / den
          + bias[t] + resid[(size_t)d * HID + t];

  // LayerNorm + ELU
  float s1 = v, s2 = v * v;
  #pragma unroll
  for (int mm = 32; mm >= 1; mm >>= 1) {
    s1 += __shfl_xor(s1, mm);
    s2 += __shfl_xor(s2, mm);
  }
  __shared__ float a1[4], a2[4];
  if (lane == 0) { a1[wave] = s1; a2[wave] = s2; }
  __syncthreads();
  float S1 = a1[0] + a1[1] + a1[2] + a1[3];
  float S2 = a2[0] + a2[1] + a2[2] + a2[3];
  float mu = S1 * (1.f / HID);
  float var = S2 * (1.f / HID) - mu * mu;
  float r = rsqrtf(var + 1e-5f);
  float y = (v - mu) * r * gamma[t] + beta[t];
  y = (y > 0.f) ? y : expm1f(y);
  out_f32[(size_t)d * HID + t] = y;
  if (WRITE_BF16) out_bf16[(size_t)d * HID + t] = f2bf(y);
}

extern "C" void kernel_launch(void* const* d_in, const int* in_sizes, int n_in,
                              void* d_out, int out_size, void* d_ws, size_t ws_size,
                              hipStream_t stream) {
  const float* x   = (const float*)d_in[0];
  const int*   ei  = (const int*)d_in[1];
  const float* W1  = (const float*)d_in[2];
  const float* as1 = (const float*)d_in[3];
  const float* ad1 = (const float*)d_in[4];
  const float* b1  = (const float*)d_in[5];
  const float* W2  = (const float*)d_in[6];
  const float* as2 = (const float*)d_in[7];
  const float* ad2 = (const float*)d_in[8];
  const float* b2  = (const float*)d_in[9];
  const float* g1  = (const float*)d_in[10];
  const float* be1 = (const float*)d_in[11];
  const float* g2  = (const float*)d_in[12];
  const float* be2 = (const float*)d_in[13];
  const float* Wp  = (const float*)d_in[14];
  const float* bp  = (const float*)d_in[15];
  float* out = (float*)d_out;

  const size_t NB16 = (size_t)N_NODES * HID * sizeof(ushort);  // 15.36 MB
  const size_t NB32 = (size_t)N_NODES * HID * sizeof(float);   // 30.72 MB
  const size_t XB16 = (size_t)N_NODES * IN_DIM * sizeof(ushort);
  const size_t NH_BUF = (size_t)N_NODES * HEADS * sizeof(float);
  char* ws = (char*)d_ws;
  size_t off = 0;
  ushort* hbf   = (ushort*)(ws + off); off += NB16;            // h (bf16)
  ushort* hAbf  = (ushort*)(ws + off); off += NB16;            // hA (bf16)
  float*  bufB  = (float*) (ws + off); off += NB32;            // resid (f32)
  ushort* xbf   = (ushort*)(ws + off); off += XB16;
  ushort* w1t   = (ushort*)(ws + off); off += (size_t)HID * IN_DIM * 2;
  ushort* wpt   = (ushort*)(ws + off); off += (size_t)HID * IN_DIM * 2;
  ushort* w2t   = (ushort*)(ws + off); off += (size_t)HID * HID * 2;
  float*  esrc  = (float*) (ws + off); off += NH_BUF;
  float*  edstb = (float*) (ws + off); off += NH_BUF;
  float*  pcsr  = (float*) (ws + off); off += (size_t)ETOT * HEADS * 4;  // 8.16MB
  int*    deg    = (int*)(ws + off); off += (size_t)N_NODES * 4;
  int*    rowptr = (int*)(ws + off); off += (size_t)(N_NODES + 1) * 4;
  int*    cursor = (int*)(ws + off); off += (size_t)N_NODES * 4;
  int*    col    = (int*)(ws + off); off += (size_t)ETOT * 4;
  int*    dstc   = (int*)(ws + off); off += (size_t)ETOT * 4;

  // ---- CSR build (shared by both layers) ----
  hipMemsetAsync(deg, 0, (size_t)N_NODES * 4, stream);
  deg_count<<<cdiv(ETOT, 256), 256, 0, stream>>>(ei, deg);
  scan_rowptr<<<1, 1024, 0, stream>>>(deg, rowptr, cursor);
  scatter_edges<<<cdiv(ETOT, 256), 256, 0, stream>>>(ei, cursor, col, dstc);

  // ---- precision prep (x conv + 3 weight transposes) ----
  prep<<<3750 + 128 + 128 + 256, 256, 0, stream>>>(x, W1, Wp, W2, xbf, w1t, wpt, w2t);

  dim3 gemm_grid(cdiv(N_NODES, 128), 2);

  // ================= Layer 1 =================
  gemm_mfma<IN_DIM, true ><<<gemm_grid, 256, 0, stream>>>(xbf, w1t, nullptr, hbf, N_NODES);
  gemm_mfma<IN_DIM, false><<<gemm_grid, 256, 0, stream>>>(xbf, wpt, bp, bufB, N_NODES);
  attn_logits<<<N_NODES, 256, 0, stream>>>(hbf, as1, ad1, esrc, edstb);
  edge_alpha<<<cdiv(ETOT, 256), 256, 0, stream>>>(col, dstc, esrc, edstb, pcsr);
  gat_agg<true><<<N_NODES, 256, 0, stream>>>(rowptr, col, pcsr, hbf, b1, bufB,
                                             g1, be1, bufB, hAbf);

  // ================= Layer 2 =================
  gemm_mfma<HID, true><<<gemm_grid, 256, 0, stream>>>(hAbf, w2t, nullptr, hbf, N_NODES);
  attn_logits<<<N_NODES, 256, 0, stream>>>(hbf, as2, ad2, esrc, edstb);
  edge_alpha<<<cdiv(ETOT, 256), 256, 0, stream>>>(col, dstc, esrc, edstb, pcsr);
  gat_agg<false><<<N_NODES, 256, 0, stream>>>(rowptr, col, pcsr, hbf, b2, bufB,
                                              g2, be2, out, nullptr);
}

// Round 5
// 265.488 us; speedup vs baseline: 5.0163x; 1.3277x over previous
//
#include <hip/hip_runtime.h>
#include <cstdint>
#include <cstddef>

#define N_NODES 30000
#define E_EDGES 480000
#define ETOT    510000   // E + N self-loops
#define IN_DIM  128
#define HID     256
#define HEADS   4
#define NEG_SLOPE 0.2f

static inline int cdiv(int a, int b){ return (a + b - 1) / b; }

typedef short bf16x8 __attribute__((ext_vector_type(8)));
typedef float f32x4  __attribute__((ext_vector_type(4)));

__device__ __forceinline__ unsigned short f2bf(float f) {
  unsigned u = __float_as_uint(f);
  unsigned r = (u + 0x7FFFu + ((u >> 16) & 1u)) >> 16;   // RNE
  return (unsigned short)r;
}
__device__ __forceinline__ float bf2f(unsigned short s) {
  return __uint_as_float((unsigned)s << 16);
}

// ---- prep: x->bf16 (3750 blocks) + W1/Wp/W2 transpose->bf16 ----
__global__ __launch_bounds__(256) void prep(
    const float* __restrict__ x, const float* __restrict__ W1,
    const float* __restrict__ Wp, const float* __restrict__ W2,
    ushort* __restrict__ xbf, ushort* __restrict__ w1t,
    ushort* __restrict__ wpt, ushort* __restrict__ w2t)
{
  int b = blockIdx.x;
  int t = threadIdx.x;
  if (b < 3750) {                       // 3750*256*4 = 3.84M = N*IN
    int i = b * 256 + t;
    float4 v = ((const float4*)x)[i];
    ushort4 o;
    o.x = f2bf(v.x); o.y = f2bf(v.y); o.z = f2bf(v.z); o.w = f2bf(v.w);
    ((ushort4*)xbf)[i] = o;
  } else if (b < 3750 + 128) {
    int k = b - 3750;
    w1t[(size_t)t * IN_DIM + k] = f2bf(W1[(size_t)k * HID + t]);
  } else if (b < 3750 + 256) {
    int k = b - 3878;
    wpt[(size_t)t * IN_DIM + k] = f2bf(Wp[(size_t)k * HID + t]);
  } else {
    int k = b - 4006;
    w2t[(size_t)t * HID + k] = f2bf(W2[(size_t)k * HID + t]);
  }
}

// ---- bf16 MFMA GEMM: C[n x 256] = A[n x K] @ WT^T (+bias opt) ----
// block = 256 thr = 4 waves (2x2), block tile 128x128, wave tile 64x64.
// ATTN: fused e_src/e_dst head-dot epilogue (wave tile == one head's 64 cols)
template<int K, bool OUT_BF16, bool ATTN>
__global__ __launch_bounds__(256) void gemm_mfma(
    const ushort* __restrict__ A,    // [n][K] bf16
    const ushort* __restrict__ WT,   // [256][K] bf16
    const float* __restrict__ bias,  // nullable
    const float* __restrict__ att_src, const float* __restrict__ att_dst,
    void* __restrict__ Cout, float* __restrict__ esrc,
    float* __restrict__ edst, int n)
{
  const int wave = threadIdx.x >> 6;
  const int lane = threadIdx.x & 63;
  const int wr = wave >> 1, wc = wave & 1;
  const int brow = blockIdx.x * 128 + wr * 64;
  const int bcol = blockIdx.y * 128 + wc * 64;
  const int lrow = lane & 15;
  const int kgrp = lane >> 4;       // 0..3

  f32x4 acc[4][4] = {};
  for (int k0 = 0; k0 < K; k0 += 32) {
    const int kb = k0 + kgrp * 8;
    bf16x8 a[4], b[4];
    #pragma unroll
    for (int mi = 0; mi < 4; ++mi) {
      int r = brow + mi * 16 + lrow;
      r = min(r, n - 1);
      a[mi] = *(const bf16x8*)&A[(size_t)r * K + kb];
    }
    #pragma unroll
    for (int ni = 0; ni < 4; ++ni) {
      int c = bcol + ni * 16 + lrow;
      b[ni] = *(const bf16x8*)&WT[(size_t)c * K + kb];
    }
    #pragma unroll
    for (int mi = 0; mi < 4; ++mi)
      #pragma unroll
      for (int ni = 0; ni < 4; ++ni)
        acc[mi][ni] = __builtin_amdgcn_mfma_f32_16x16x32_bf16(a[mi], b[ni], acc[mi][ni], 0, 0, 0);
  }
  // C write (C/D layout: col=lane&15, row=(lane>>4)*4+reg — m89-verified)
  #pragma unroll
  for (int mi = 0; mi < 4; ++mi) {
    #pragma unroll
    for (int r = 0; r < 4; ++r) {
      int row = brow + mi * 16 + kgrp * 4 + r;
      if (row < n) {
        #pragma unroll
        for (int ni = 0; ni < 4; ++ni) {
          int colg = bcol + ni * 16 + lrow;
          float v = acc[mi][ni][r];
          if (bias) v += bias[colg];
          if (OUT_BF16) ((ushort*)Cout)[(size_t)row * HID + colg] = f2bf(v);
          else          ((float*) Cout)[(size_t)row * HID + colg] = v;
        }
      }
    }
  }
  // fused attention-logit epilogue: this wave's 64 cols == head hh
  if (ATTN) {
    const int hh = blockIdx.y * 2 + wc;
    float as[4], ad[4];
    #pragma unroll
    for (int ni = 0; ni < 4; ++ni) {
      as[ni] = att_src[hh * 64 + ni * 16 + lrow];
      ad[ni] = att_dst[hh * 64 + ni * 16 + lrow];
    }
    #pragma unroll
    for (int mi = 0; mi < 4; ++mi) {
      #pragma unroll
      for (int r = 0; r < 4; ++r) {
        float vs = 0.f, vd = 0.f;
        #pragma unroll
        for (int ni = 0; ni < 4; ++ni) {
          float c = acc[mi][ni][r];
          vs += c * as[ni];
          vd += c * ad[ni];
        }
        #pragma unroll
        for (int m = 1; m <= 8; m <<= 1) {   // reduce over lrow (16 lanes)
          vs += __shfl_xor(vs, m);
          vd += __shfl_xor(vd, m);
        }
        int row = brow + mi * 16 + kgrp * 4 + r;
        if (lrow == 0 && row < n) {
          esrc[row * HEADS + hh] = vs;
          edst[row * HEADS + hh] = vd;
        }
      }
    }
  }
}

// ================= CSR build =================
__global__ __launch_bounds__(256) void deg_count(const int* __restrict__ ei,
                                                 int* __restrict__ deg)
{
  int e = blockIdx.x * blockDim.x + threadIdx.x;
  if (e >= ETOT) return;
  int d = (e < E_EDGES) ? ei[E_EDGES + e] : (e - E_EDGES);
  atomicAdd(&deg[d], 1);
}

__global__ __launch_bounds__(1024) void scan_rowptr(const int* __restrict__ deg,
                                                    int* __restrict__ rowptr,
                                                    int* __restrict__ cursor)
{
  const int CE = 30;
  __shared__ int sc[1024];
  int t = threadIdx.x;
  int base = t * CE;
  int local[CE];
  int s = 0;
  #pragma unroll
  for (int i = 0; i < CE; ++i) {
    int idx = base + i;
    int v = (idx < N_NODES) ? deg[idx] : 0;
    local[i] = s;
    s += v;
  }
  sc[t] = s;
  __syncthreads();
  for (int o = 1; o < 1024; o <<= 1) {
    int v = (t >= o) ? sc[t - o] : 0;
    __syncthreads();
    sc[t] += v;
    __syncthreads();
  }
  int off = sc[t] - s;
  #pragma unroll
  for (int i = 0; i < CE; ++i) {
    int idx = base + i;
    if (idx < N_NODES) {
      rowptr[idx] = off + local[i];
      cursor[idx] = off + local[i];
    }
  }
  if (t == 1023) rowptr[N_NODES] = off + s;
}

__global__ __launch_bounds__(256) void scatter_edges(const int* __restrict__ ei,
                                                     int* __restrict__ cursor,
                                                     int* __restrict__ col)
{
  int e = blockIdx.x * blockDim.x + threadIdx.x;
  if (e >= ETOT) return;
  int s, d;
  if (e < E_EDGES) { s = ei[e]; d = ei[E_EDGES + e]; }
  else             { s = d = e - E_EDGES; }
  int pos = atomicAdd(&cursor[d], 1);
  col[pos] = s;
}

// ========== fused aggregation: one WAVE per dst node, no LDS/barriers ==========
// lane: slot = lane>>5 (edge parity), channels (lane&31)*8 .. +7
// p computed inline (max-free exp — validated R4); denom + LN via shfl only.
template<bool WRITE_BF16>
__global__ __launch_bounds__(256) void gat_agg(
    const int* __restrict__ rowptr, const int* __restrict__ col,
    const float* __restrict__ esrc, const float* __restrict__ edst,
    const ushort* __restrict__ h, const float* __restrict__ bias,
    const ushort* __restrict__ resid, const float* __restrict__ gamma,
    const float* __restrict__ beta, float* __restrict__ out_f32,
    ushort* __restrict__ out_bf16)
{
  const int wave = threadIdx.x >> 6;
  const int lane = threadIdx.x & 63;
  const int d = blockIdx.x * 4 + wave;        // grid = 7500 exact
  const int slot = lane >> 5;                  // 0,1
  const int cblk = (lane & 31) * 8;            // channel base 0..248
  const int headc = cblk >> 6;                 // head of this channel block
  const int r0 = rowptr[d], r1 = rowptr[d + 1];

  const float4 ed4 = ((const float4*)edst)[d];
  float acc[8] = {};
  float dp0 = 0.f, dp1 = 0.f, dp2 = 0.f, dp3 = 0.f;

  for (int j = r0 + slot; j < r1; j += 2) {
    int s = col[j];                             // wave-uniform -> broadcast
    float4 es = ((const float4*)esrc)[s];
    float v0 = es.x + ed4.x; v0 = (v0 >= 0.f) ? v0 : NEG_SLOPE * v0;
    float v1 = es.y + ed4.y; v1 = (v1 >= 0.f) ? v1 : NEG_SLOPE * v1;
    float v2 = es.z + ed4.z; v2 = (v2 >= 0.f) ? v2 : NEG_SLOPE * v2;
    float v3 = es.w + ed4.w; v3 = (v3 >= 0.f) ? v3 : NEG_SLOPE * v3;
    float p0 = __expf(v0), p1 = __expf(v1), p2 = __expf(v2), p3 = __expf(v3);
    dp0 += p0; dp1 += p1; dp2 += p2; dp3 += p3;
    float p = (headc == 0) ? p0 : (headc == 1) ? p1 : (headc == 2) ? p2 : p3;
    bf16x8 hv = *(const bf16x8*)&h[(size_t)s * HID + cblk];  // 16B/lane coalesced
    #pragma unroll
    for (int k = 0; k < 8; ++k) acc[k] += bf2f((unsigned short)hv[k]) * p;
  }

  // combine the two edge-parity slots (lane l <-> l^32)
  #pragma unroll
  for (int k = 0; k < 8; ++k) acc[k] += __shfl_xor(acc[k], 32);
  dp0 += __shfl_xor(dp0, 32); dp1 += __shfl_xor(dp1, 32);
  dp2 += __shfl_xor(dp2, 32); dp3 += __shfl_xor(dp3, 32);
  float den = (headc == 0) ? dp0 : (headc == 1) ? dp1 : (headc == 2) ? dp2 : dp3;
  float rden = 1.f / den;

  // v = agg/den + bias + resid
  bf16x8 rv = *(const bf16x8*)&resid[(size_t)d * HID + cblk];
  float4 ba = *(const float4*)&bias[cblk];
  float4 bb = *(const float4*)&bias[cblk + 4];
  float v[8];
  v[0] = acc[0] * rden + ba.x + bf2f((unsigned short)rv[0]);
  v[1] = acc[1] * rden + ba.y + bf2f((unsigned short)rv[1]);
  v[2] = acc[2] * rden + ba.z + bf2f((unsigned short)rv[2]);
  v[3] = acc[3] * rden + ba.w + bf2f((unsigned short)rv[3]);
  v[4] = acc[4] * rden + bb.x + bf2f((unsigned short)rv[4]);
  v[5] = acc[5] * rden + bb.y + bf2f((unsigned short)rv[5]);
  v[6] = acc[6] * rden + bb.z + bf2f((unsigned short)rv[6]);
  v[7] = acc[7] * rden + bb.w + bf2f((unsigned short)rv[7]);

  // LayerNorm stats (channels duplicated across the two slots -> /512)
  float s1 = 0.f, s2 = 0.f;
  #pragma unroll
  for (int k = 0; k < 8; ++k) { s1 += v[k]; s2 += v[k] * v[k]; }
  #pragma unroll
  for (int m = 32; m >= 1; m >>= 1) {
    s1 += __shfl_xor(s1, m);
    s2 += __shfl_xor(s2, m);
  }
  float mu = s1 * (1.f / 512.f);
  float var = s2 * (1.f / 512.f) - mu * mu;
  float rr = rsqrtf(var + 1e-5f);

  if (slot == 0) {
    float4 ga = *(const float4*)&gamma[cblk];
    float4 gb = *(const float4*)&gamma[cblk + 4];
    float4 ea = *(const float4*)&beta[cblk];
    float4 eb = *(const float4*)&beta[cblk + 4];
    float g[8] = { ga.x, ga.y, ga.z, ga.w, gb.x, gb.y, gb.z, gb.w };
    float e[8] = { ea.x, ea.y, ea.z, ea.w, eb.x, eb.y, eb.z, eb.w };
    float y[8];
    #pragma unroll
    for (int k = 0; k < 8; ++k) {
      float t = (v[k] - mu) * rr * g[k] + e[k];
      y[k] = (t > 0.f) ? t : expm1f(t);
    }
    if (WRITE_BF16) {
      bf16x8 o;
      #pragma unroll
      for (int k = 0; k < 8; ++k) o[k] = (short)f2bf(y[k]);
      *(bf16x8*)&out_bf16[(size_t)d * HID + cblk] = o;
    } else {
      float4 o0 = { y[0], y[1], y[2], y[3] };
      float4 o1 = { y[4], y[5], y[6], y[7] };
      *(float4*)&out_f32[(size_t)d * HID + cblk] = o0;
      *(float4*)&out_f32[(size_t)d * HID + cblk + 4] = o1;
    }
  }
}

extern "C" void kernel_launch(void* const* d_in, const int* in_sizes, int n_in,
                              void* d_out, int out_size, void* d_ws, size_t ws_size,
                              hipStream_t stream) {
  const float* x   = (const float*)d_in[0];
  const int*   ei  = (const int*)d_in[1];
  const float* W1  = (const float*)d_in[2];
  const float* as1 = (const float*)d_in[3];
  const float* ad1 = (const float*)d_in[4];
  const float* b1  = (const float*)d_in[5];
  const float* W2  = (const float*)d_in[6];
  const float* as2 = (const float*)d_in[7];
  const float* ad2 = (const float*)d_in[8];
  const float* b2  = (const float*)d_in[9];
  const float* g1  = (const float*)d_in[10];
  const float* be1 = (const float*)d_in[11];
  const float* g2  = (const float*)d_in[12];
  const float* be2 = (const float*)d_in[13];
  const float* Wp  = (const float*)d_in[14];
  const float* bp  = (const float*)d_in[15];
  float* out = (float*)d_out;

  const size_t NB16 = (size_t)N_NODES * HID * sizeof(ushort);  // 15.36 MB
  const size_t XB16 = (size_t)N_NODES * IN_DIM * sizeof(ushort);
  const size_t NH_BUF = (size_t)N_NODES * HEADS * sizeof(float);
  char* ws = (char*)d_ws;
  size_t off = 0;
  ushort* hbf   = (ushort*)(ws + off); off += NB16;            // h (bf16)
  ushort* hAbf  = (ushort*)(ws + off); off += NB16;            // hA / layer-2 resid
  ushort* rbf   = (ushort*)(ws + off); off += NB16;            // layer-1 resid (bf16)
  ushort* xbf   = (ushort*)(ws + off); off += XB16;
  ushort* w1t   = (ushort*)(ws + off); off += (size_t)HID * IN_DIM * 2;
  ushort* wpt   = (ushort*)(ws + off); off += (size_t)HID * IN_DIM * 2;
  ushort* w2t   = (ushort*)(ws + off); off += (size_t)HID * HID * 2;
  float*  esrc  = (float*) (ws + off); off += NH_BUF;
  float*  edstb = (float*) (ws + off); off += NH_BUF;
  int*    deg    = (int*)(ws + off); off += (size_t)N_NODES * 4;
  int*    rowptr = (int*)(ws + off); off += (size_t)(N_NODES + 1) * 4;
  int*    cursor = (int*)(ws + off); off += (size_t)N_NODES * 4;
  int*    col    = (int*)(ws + off); off += (size_t)ETOT * 4;

  // ---- CSR build (shared by both layers) ----
  hipMemsetAsync(deg, 0, (size_t)N_NODES * 4, stream);
  deg_count<<<cdiv(ETOT, 256), 256, 0, stream>>>(ei, deg);
  scan_rowptr<<<1, 1024, 0, stream>>>(deg, rowptr, cursor);
  scatter_edges<<<cdiv(ETOT, 256), 256, 0, stream>>>(ei, cursor, col);

  // ---- precision prep (x conv + 3 weight transposes) ----
  prep<<<3750 + 128 + 128 + 256, 256, 0, stream>>>(x, W1, Wp, W2, xbf, w1t, wpt, w2t);

  dim3 gemm_grid(cdiv(N_NODES, 128), 2);

  // ================= Layer 1 =================
  gemm_mfma<IN_DIM, true, true ><<<gemm_grid, 256, 0, stream>>>(
      xbf, w1t, nullptr, as1, ad1, hbf, esrc, edstb, N_NODES);
  gemm_mfma<IN_DIM, true, false><<<gemm_grid, 256, 0, stream>>>(
      xbf, wpt, bp, nullptr, nullptr, rbf, nullptr, nullptr, N_NODES);
  gat_agg<true><<<N_NODES / 4, 256, 0, stream>>>(
      rowptr, col, esrc, edstb, hbf, b1, rbf, g1, be1, nullptr, hAbf);

  // ================= Layer 2 =================
  gemm_mfma<HID, true, true><<<gemm_grid, 256, 0, stream>>>(
      hAbf, w2t, nullptr, as2, ad2, hbf, esrc, edstb, N_NODES);
  gat_agg<false><<<N_NODES / 4, 256, 0, stream>>>(
      rowptr, col, esrc, edstb, hbf, b2, hAbf, g2, be2, out, nullptr);
}

// Round 6
// 258.466 us; speedup vs baseline: 5.1525x; 1.0272x over previous
//
#include <hip/hip_runtime.h>
#include <cstdint>
#include <cstddef>

#define N_NODES 30000
#define E_EDGES 480000
#define ETOT    510000   // E + N self-loops
#define IN_DIM  128
#define HID     256
#define HEADS   4
#define NEG_SLOPE 0.2f
#define DEG_BLOCKS 1993  // cdiv(ETOT,256)

static inline int cdiv(int a, int b){ return (a + b - 1) / b; }

typedef short bf16x8 __attribute__((ext_vector_type(8)));
typedef float f32x4  __attribute__((ext_vector_type(4)));

__device__ __forceinline__ unsigned short f2bf(float f) {
  unsigned u = __float_as_uint(f);
  unsigned r = (u + 0x7FFFu + ((u >> 16) & 1u)) >> 16;   // RNE
  return (unsigned short)r;
}
__device__ __forceinline__ float bf2f(unsigned short s) {
  return __uint_as_float((unsigned)s << 16);
}

// ---- setup: deg_count (blocks 0..1992) + x->bf16 + W transposes ----
__global__ __launch_bounds__(256) void setup(
    const int* __restrict__ ei, int* __restrict__ deg,
    const float* __restrict__ x, const float* __restrict__ W1,
    const float* __restrict__ Wp, const float* __restrict__ W2,
    ushort* __restrict__ xbf, ushort* __restrict__ w1t,
    ushort* __restrict__ wpt, ushort* __restrict__ w2t)
{
  int b = blockIdx.x;
  int t = threadIdx.x;
  if (b < DEG_BLOCKS) {
    int e = b * 256 + t;
    if (e < ETOT) {
      int d = (e < E_EDGES) ? ei[E_EDGES + e] : (e - E_EDGES);
      atomicAdd(&deg[d], 1);
    }
    return;
  }
  b -= DEG_BLOCKS;
  if (b < 3750) {                       // 3750*256*4 = N*IN
    int i = b * 256 + t;
    float4 v = ((const float4*)x)[i];
    ushort4 o;
    o.x = f2bf(v.x); o.y = f2bf(v.y); o.z = f2bf(v.z); o.w = f2bf(v.w);
    ((ushort4*)xbf)[i] = o;
  } else if (b < 3750 + 128) {
    int k = b - 3750;
    w1t[(size_t)t * IN_DIM + k] = f2bf(W1[(size_t)k * HID + t]);
  } else if (b < 3750 + 256) {
    int k = b - 3878;
    wpt[(size_t)t * IN_DIM + k] = f2bf(Wp[(size_t)k * HID + t]);
  } else {
    int k = b - 4006;
    w2t[(size_t)t * HID + k] = f2bf(W2[(size_t)k * HID + t]);
  }
}

// ---- bf16 MFMA GEMM + fused attn-logit epilogue (+ fused proj for layer 1) ----
// block = 256 thr = 4 waves (2x2), block tile 128x128, wave tile 64x64.
// L1: grid.y = 4, cols 0..255 -> hout + attn; cols 256..511 -> rout (+pbias).
template<int K, bool L1>
__global__ __launch_bounds__(256) void gemm_fused(
    const ushort* __restrict__ A,    // [n][K] bf16
    const ushort* __restrict__ WT,   // [NOUT][K] bf16 (W1t | Wpt contiguous for L1)
    const float* __restrict__ att_src, const float* __restrict__ att_dst,
    ushort* __restrict__ hout, float* __restrict__ esrc, float* __restrict__ edst,
    ushort* __restrict__ rout, const float* __restrict__ pbias, int n)
{
  const int wave = threadIdx.x >> 6;
  const int lane = threadIdx.x & 63;
  const int wr = wave >> 1, wc = wave & 1;
  const int brow = blockIdx.x * 128 + wr * 64;
  const int bcol = blockIdx.y * 128 + wc * 64;
  const int lrow = lane & 15;
  const int kgrp = lane >> 4;       // 0..3

  f32x4 acc[4][4] = {};
  for (int k0 = 0; k0 < K; k0 += 32) {
    const int kb = k0 + kgrp * 8;
    bf16x8 a[4], b[4];
    #pragma unroll
    for (int mi = 0; mi < 4; ++mi) {
      int r = brow + mi * 16 + lrow;
      r = min(r, n - 1);
      a[mi] = *(const bf16x8*)&A[(size_t)r * K + kb];
    }
    #pragma unroll
    for (int ni = 0; ni < 4; ++ni) {
      int c = bcol + ni * 16 + lrow;
      b[ni] = *(const bf16x8*)&WT[(size_t)c * K + kb];
    }
    #pragma unroll
    for (int mi = 0; mi < 4; ++mi)
      #pragma unroll
      for (int ni = 0; ni < 4; ++ni)
        acc[mi][ni] = __builtin_amdgcn_mfma_f32_16x16x32_bf16(a[mi], b[ni], acc[mi][ni], 0, 0, 0);
  }
  const bool proj = L1 && (bcol >= 256);
  // C write (C/D layout: col=lane&15, row=(lane>>4)*4+reg — m89-verified)
  #pragma unroll
  for (int mi = 0; mi < 4; ++mi) {
    #pragma unroll
    for (int r = 0; r < 4; ++r) {
      int row = brow + mi * 16 + kgrp * 4 + r;
      if (row < n) {
        #pragma unroll
        for (int ni = 0; ni < 4; ++ni) {
          int colg = bcol + ni * 16 + lrow;
          float v = acc[mi][ni][r];
          if (proj) {
            int c = colg - 256;
            rout[(size_t)row * HID + c] = f2bf(v + pbias[c]);
          } else {
            hout[(size_t)row * HID + colg] = f2bf(v);
          }
        }
      }
    }
  }
  // fused attention-logit epilogue: wave's 64 cols == head (bcol>>6)
  if (!proj) {
    const int hh = bcol >> 6;
    float as[4], ad[4];
    #pragma unroll
    for (int ni = 0; ni < 4; ++ni) {
      as[ni] = att_src[hh * 64 + ni * 16 + lrow];
      ad[ni] = att_dst[hh * 64 + ni * 16 + lrow];
    }
    #pragma unroll
    for (int mi = 0; mi < 4; ++mi) {
      #pragma unroll
      for (int r = 0; r < 4; ++r) {
        float vs = 0.f, vd = 0.f;
        #pragma unroll
        for (int ni = 0; ni < 4; ++ni) {
          float c = acc[mi][ni][r];
          vs += c * as[ni];
          vd += c * ad[ni];
        }
        #pragma unroll
        for (int m = 1; m <= 8; m <<= 1) {
          vs += __shfl_xor(vs, m);
          vd += __shfl_xor(vd, m);
        }
        int row = brow + mi * 16 + kgrp * 4 + r;
        if (lrow == 0 && row < n) {
          esrc[row * HEADS + hh] = vs;
          edst[row * HEADS + hh] = vd;
        }
      }
    }
  }
}

// ================= CSR build =================
__global__ __launch_bounds__(1024) void scan_rowptr(const int* __restrict__ deg,
                                                    int* __restrict__ rowptr,
                                                    int* __restrict__ cursor)
{
  const int CE = 30;
  __shared__ int sc[1024];
  int t = threadIdx.x;
  int base = t * CE;
  int local[CE];
  int s = 0;
  #pragma unroll
  for (int i = 0; i < CE; ++i) {
    int idx = base + i;
    int v = (idx < N_NODES) ? deg[idx] : 0;
    local[i] = s;
    s += v;
  }
  sc[t] = s;
  __syncthreads();
  for (int o = 1; o < 1024; o <<= 1) {
    int v = (t >= o) ? sc[t - o] : 0;
    __syncthreads();
    sc[t] += v;
    __syncthreads();
  }
  int off = sc[t] - s;
  #pragma unroll
  for (int i = 0; i < CE; ++i) {
    int idx = base + i;
    if (idx < N_NODES) {
      rowptr[idx] = off + local[i];
      cursor[idx] = off + local[i];
    }
  }
  if (t == 1023) rowptr[N_NODES] = off + s;
}

__global__ __launch_bounds__(256) void scatter_edges(const int* __restrict__ ei,
                                                     int* __restrict__ cursor,
                                                     int* __restrict__ col)
{
  int e = blockIdx.x * blockDim.x + threadIdx.x;
  if (e >= ETOT) return;
  int s, d;
  if (e < E_EDGES) { s = ei[e]; d = ei[E_EDGES + e]; }
  else             { s = d = e - E_EDGES; }
  int pos = atomicAdd(&cursor[d], 1);
  col[pos] = s;
}

// ========== fused aggregation: one WAVE per dst node, no LDS/barriers ==========
// lane: slot = lane>>4 (edge mod 4), channels (lane&15)*16 .. +15
// single-head exp per lane (max-free exp validated R4/R5)
template<bool WRITE_BF16>
__global__ __launch_bounds__(256) void gat_agg(
    const int* __restrict__ rowptr, const int* __restrict__ col,
    const float* __restrict__ esrc, const float* __restrict__ edst,
    const ushort* __restrict__ h, const float* __restrict__ bias,
    const ushort* __restrict__ resid, const float* __restrict__ gamma,
    const float* __restrict__ beta, float* __restrict__ out_f32,
    ushort* __restrict__ out_bf16)
{
  const int wave = threadIdx.x >> 6;
  const int lane = threadIdx.x & 63;
  const int d = blockIdx.x * 4 + wave;        // grid = 7500 exact
  const int slot = lane >> 4;                  // 0..3
  const int cblk = (lane & 15) * 16;           // channel base 0..240
  const int headc = cblk >> 6;                 // head of these channels
  const int r0 = rowptr[d], r1 = rowptr[d + 1];

  const float edh = edst[d * HEADS + headc];
  float acc[16] = {};
  float dp = 0.f;

  for (int j = r0 + slot; j < r1; j += 4) {
    int s = col[j];                              // 4 distinct addrs / wave
    float v = esrc[s * HEADS + headc] + edh;
    v = (v >= 0.f) ? v : NEG_SLOPE * v;
    float p = __expf(v);
    dp += p;
    const ushort* hp = &h[(size_t)s * HID + cblk];
    bf16x8 h0 = *(const bf16x8*)hp;
    bf16x8 h1 = *(const bf16x8*)(hp + 8);
    #pragma unroll
    for (int k = 0; k < 8; ++k) acc[k]     += bf2f((unsigned short)h0[k]) * p;
    #pragma unroll
    for (int k = 0; k < 8; ++k) acc[8 + k] += bf2f((unsigned short)h1[k]) * p;
  }

  // combine the 4 edge slots (channel group invariant under xor 16/32)
  #pragma unroll
  for (int k = 0; k < 16; ++k) {
    acc[k] += __shfl_xor(acc[k], 32);
    acc[k] += __shfl_xor(acc[k], 16);
  }
  dp += __shfl_xor(dp, 32);
  dp += __shfl_xor(dp, 16);
  float rden = 1.f / dp;

  // v = agg/den + bias + resid (16 channels per lane)
  float v[16];
  {
    const ushort* rp = &resid[(size_t)d * HID + cblk];
    bf16x8 rv0 = *(const bf16x8*)rp;
    bf16x8 rv1 = *(const bf16x8*)(rp + 8);
    const float4* bp4 = (const float4*)&bias[cblk];
    float4 b0 = bp4[0], b1 = bp4[1], b2 = bp4[2], b3 = bp4[3];
    const float* bb = (const float*)&b0;   // b0..b3 contiguous? not guaranteed; expand
    float bl[16] = { b0.x,b0.y,b0.z,b0.w, b1.x,b1.y,b1.z,b1.w,
                     b2.x,b2.y,b2.z,b2.w, b3.x,b3.y,b3.z,b3.w };
    (void)bb;
    #pragma unroll
    for (int k = 0; k < 8; ++k)  v[k]     = acc[k]     * rden + bl[k]     + bf2f((unsigned short)rv0[k]);
    #pragma unroll
    for (int k = 0; k < 8; ++k)  v[8 + k] = acc[8 + k] * rden + bl[8 + k] + bf2f((unsigned short)rv1[k]);
  }

  // LayerNorm stats (each channel counted 4x across slots -> /1024)
  float s1 = 0.f, s2 = 0.f;
  #pragma unroll
  for (int k = 0; k < 16; ++k) { s1 += v[k]; s2 += v[k] * v[k]; }
  #pragma unroll
  for (int m = 32; m >= 1; m >>= 1) {
    s1 += __shfl_xor(s1, m);
    s2 += __shfl_xor(s2, m);
  }
  float mu = s1 * (1.f / 1024.f);
  float var = s2 * (1.f / 1024.f) - mu * mu;
  float rr = rsqrtf(var + 1e-5f);

  if (slot == 0) {
    const float4* gp4 = (const float4*)&gamma[cblk];
    const float4* ep4 = (const float4*)&beta[cblk];
    float4 g0 = gp4[0], g1 = gp4[1], g2 = gp4[2], g3 = gp4[3];
    float4 e0 = ep4[0], e1 = ep4[1], e2 = ep4[2], e3 = ep4[3];
    float gl[16] = { g0.x,g0.y,g0.z,g0.w, g1.x,g1.y,g1.z,g1.w,
                     g2.x,g2.y,g2.z,g2.w, g3.x,g3.y,g3.z,g3.w };
    float el[16] = { e0.x,e0.y,e0.z,e0.w, e1.x,e1.y,e1.z,e1.w,
                     e2.x,e2.y,e2.z,e2.w, e3.x,e3.y,e3.z,e3.w };
    float y[16];
    #pragma unroll
    for (int k = 0; k < 16; ++k) {
      float t = (v[k] - mu) * rr * gl[k] + el[k];
      y[k] = (t > 0.f) ? t : expm1f(t);
    }
    if (WRITE_BF16) {
      bf16x8 o0, o1;
      #pragma unroll
      for (int k = 0; k < 8; ++k) { o0[k] = (short)f2bf(y[k]); o1[k] = (short)f2bf(y[8 + k]); }
      *(bf16x8*)&out_bf16[(size_t)d * HID + cblk] = o0;
      *(bf16x8*)&out_bf16[(size_t)d * HID + cblk + 8] = o1;
    } else {
      float4* op = (float4*)&out_f32[(size_t)d * HID + cblk];
      float4 o0 = { y[0], y[1], y[2], y[3] };
      float4 o1 = { y[4], y[5], y[6], y[7] };
      float4 o2 = { y[8], y[9], y[10], y[11] };
      float4 o3 = { y[12], y[13], y[14], y[15] };
      op[0] = o0; op[1] = o1; op[2] = o2; op[3] = o3;
    }
  }
}

extern "C" void kernel_launch(void* const* d_in, const int* in_sizes, int n_in,
                              void* d_out, int out_size, void* d_ws, size_t ws_size,
                              hipStream_t stream) {
  const float* x   = (const float*)d_in[0];
  const int*   ei  = (const int*)d_in[1];
  const float* W1  = (const float*)d_in[2];
  const float* as1 = (const float*)d_in[3];
  const float* ad1 = (const float*)d_in[4];
  const float* b1  = (const float*)d_in[5];
  const float* W2  = (const float*)d_in[6];
  const float* as2 = (const float*)d_in[7];
  const float* ad2 = (const float*)d_in[8];
  const float* b2  = (const float*)d_in[9];
  const float* g1  = (const float*)d_in[10];
  const float* be1 = (const float*)d_in[11];
  const float* g2  = (const float*)d_in[12];
  const float* be2 = (const float*)d_in[13];
  const float* Wp  = (const float*)d_in[14];
  const float* bp  = (const float*)d_in[15];
  float* out = (float*)d_out;

  const size_t NB16 = (size_t)N_NODES * HID * sizeof(ushort);  // 15.36 MB
  const size_t XB16 = (size_t)N_NODES * IN_DIM * sizeof(ushort);
  const size_t NH_BUF = (size_t)N_NODES * HEADS * sizeof(float);
  char* ws = (char*)d_ws;
  size_t off = 0;
  ushort* hbf   = (ushort*)(ws + off); off += NB16;            // h (bf16)
  ushort* hAbf  = (ushort*)(ws + off); off += NB16;            // hA / layer-2 resid
  ushort* rbf   = (ushort*)(ws + off); off += NB16;            // layer-1 resid (bf16)
  ushort* xbf   = (ushort*)(ws + off); off += XB16;
  ushort* w1t   = (ushort*)(ws + off); off += (size_t)HID * IN_DIM * 2;  // [w1t|wpt] contiguous
  ushort* wpt   = (ushort*)(ws + off); off += (size_t)HID * IN_DIM * 2;
  ushort* w2t   = (ushort*)(ws + off); off += (size_t)HID * HID * 2;
  float*  esrc  = (float*) (ws + off); off += NH_BUF;
  float*  edstb = (float*) (ws + off); off += NH_BUF;
  int*    deg    = (int*)(ws + off); off += (size_t)N_NODES * 4;
  int*    rowptr = (int*)(ws + off); off += (size_t)(N_NODES + 1) * 4;
  int*    cursor = (int*)(ws + off); off += (size_t)N_NODES * 4;
  int*    col    = (int*)(ws + off); off += (size_t)ETOT * 4;

  // ---- CSR build + precision prep (fused) ----
  hipMemsetAsync(deg, 0, (size_t)N_NODES * 4, stream);
  setup<<<DEG_BLOCKS + 3750 + 128 + 128 + 256, 256, 0, stream>>>(
      ei, deg, x, W1, Wp, W2, xbf, w1t, wpt, w2t);
  scan_rowptr<<<1, 1024, 0, stream>>>(deg, rowptr, cursor);
  scatter_edges<<<cdiv(ETOT, 256), 256, 0, stream>>>(ei, cursor, col);

  // ================= Layer 1 (W1 and Wp fused: 512 output cols) =================
  gemm_fused<IN_DIM, true><<<dim3(cdiv(N_NODES, 128), 4), 256, 0, stream>>>(
      xbf, w1t, as1, ad1, hbf, esrc, edstb, rbf, bp, N_NODES);
  gat_agg<true><<<N_NODES / 4, 256, 0, stream>>>(
      rowptr, col, esrc, edstb, hbf, b1, rbf, g1, be1, nullptr, hAbf);

  // ================= Layer 2 =================
  gemm_fused<HID, false><<<dim3(cdiv(N_NODES, 128), 2), 256, 0, stream>>>(
      hAbf, w2t, as2, ad2, hbf, esrc, edstb, nullptr, nullptr, N_NODES);
  gat_agg<false><<<N_NODES / 4, 256, 0, stream>>>(
      rowptr, col, esrc, edstb, hbf, b2, hAbf, g2, be2, out, nullptr);
}